// Round 1
// baseline (771587.793 us; speedup 1.0000x reference)
//
#include <hip/hip_runtime.h>
#include <cmath>

#define B_   8192
#define V_   101
#define T_   30
#define C_   4
#define D_   64
#define HID_ 128

// LDS layout (float offsets). Row stride 68 (=64+4) breaks bank-conflict
// patterns and keeps float4 (16B) alignment. All offsets % 4 == 0.
#define OFF_DYN 0        // 101*101 = 10201 (pad to 10204)
#define OFF_H   10204    // 101*68 = 6868
#define OFF_F   17072    // 6868
#define OFF_G   23940    // 6868
#define OFF_RH  30808    // 6868
#define OFF_XT  37676    // 404
#define OFF_Y   38080    // 404
#define LDS_FLOATS 38484 // 153,936 bytes

__device__ __forceinline__ float sigmoidf_(float x) {
    return 1.0f / (1.0f + expf(-x));
}

extern "C" __global__ void __launch_bounds__(1024)
mgcgru_fused(const float* __restrict__ x,  const float* __restrict__ dyn,
             const float* __restrict__ W1, const float* __restrict__ b1,
             const float* __restrict__ W2, const float* __restrict__ b2,
             const float* __restrict__ Wz, const float* __restrict__ bz,
             const float* __restrict__ Wr, const float* __restrict__ br,
             const float* __restrict__ Ww, const float* __restrict__ bw,
             const float* __restrict__ Wf1,const float* __restrict__ bf1,
             const float* __restrict__ Wf2,const float* __restrict__ bf2,
             float* __restrict__ out)
{
    extern __shared__ float lds[];
    const int tid = threadIdx.x;
    const int b   = blockIdx.x;

    // ---- one-time: load dyn into LDS, zero h ----
    for (int i = tid; i < V_ * V_; i += 1024) lds[OFF_DYN + i] = dyn[i];
    for (int i = tid; i < V_ * 68; i += 1024) lds[OFF_H + i] = 0.0f;
    __syncthreads();

    // compute-phase ownership: dg selects 4 consecutive d, rg selects rows
    const int dg = tid & 15;       // d4 = 4*dg
    const int rg = tid >> 4;       // 0..63
    const int d4 = dg * 4;
    const int u0 = rg;             // always valid (u0 < 101)
    const int u1 = rg + 64;        // valid iff rg < 37
    const bool has_u1 = (u1 < V_);
    const int u1c = has_u1 ? u1 : u0;  // clamped safe address

    const float* xb = x + (long long)b * (V_ * T_ * C_);

    for (int t = 0; t < T_; ++t) {
        // ---- P1: load x_t tile (101 x 4) ----
        if (tid < V_ * C_) {
            int v = tid >> 2, c = tid & 3;
            lds[OFF_XT + tid] = xb[v * (T_ * C_) + t * C_ + c];
        }
        __syncthreads();

        // ---- P2: y = dyn @ xt  (101 x 4) ----
        if (tid < V_ * C_) {
            int u = tid >> 2, c = tid & 3;
            float acc = 0.0f;
            const float* dr = &lds[OFF_DYN + u * V_];
            for (int v = 0; v < V_; ++v)
                acc += dr[v] * lds[OFF_XT + v * 4 + c];
            lds[OFF_Y + tid] = acc;
        }
        __syncthreads();

        // ---- P3: f1 = tanh(y @ W1 + b1)  (101 x 64) ----
        {
            int d = tid & 63;
            int uu = tid >> 6;   // 0..15
            float bb = b1[d];
            float w0 = W1[0 * 64 + d], w1 = W1[1 * 64 + d],
                  w2 = W1[2 * 64 + d], w3 = W1[3 * 64 + d];
            for (int u = uu; u < V_; u += 16) {
                float acc = bb;
                acc += lds[OFF_Y + u * 4 + 0] * w0;
                acc += lds[OFF_Y + u * 4 + 1] * w1;
                acc += lds[OFF_Y + u * 4 + 2] * w2;
                acc += lds[OFF_Y + u * 4 + 3] * w3;
                lds[OFF_F + u * 68 + d] = tanhf(acc);
            }
        }
        __syncthreads();

        // ---- P4: g = dyn @ f1  (101 x 64) ----
        {
            float a0x = 0, a0y = 0, a0z = 0, a0w = 0;
            float a1x = 0, a1y = 0, a1z = 0, a1w = 0;
            const float* dr0 = &lds[OFF_DYN + u0 * V_];
            const float* dr1 = &lds[OFF_DYN + u1c * V_];
            for (int v = 0; v < V_; ++v) {
                float4 fv = *(const float4*)&lds[OFF_F + v * 68 + d4];
                float w0 = dr0[v];
                float w1v = dr1[v];
                a0x += w0 * fv.x;  a0y += w0 * fv.y;
                a0z += w0 * fv.z;  a0w += w0 * fv.w;
                a1x += w1v * fv.x; a1y += w1v * fv.y;
                a1z += w1v * fv.z; a1w += w1v * fv.w;
            }
            float4 s0 = {a0x, a0y, a0z, a0w};
            *(float4*)&lds[OFF_G + u0 * 68 + d4] = s0;
            if (has_u1) {
                float4 s1 = {a1x, a1y, a1z, a1w};
                *(float4*)&lds[OFF_G + u1 * 68 + d4] = s1;
            }
        }
        __syncthreads();

        // ---- P5: f = tanh(g @ W2 + b2)  (101 x 64) ----
        {
            float a0x = 0, a0y = 0, a0z = 0, a0w = 0;
            float a1x = 0, a1y = 0, a1z = 0, a1w = 0;
            for (int k = 0; k < D_; ++k) {
                float4 w = *(const float4*)&W2[k * 64 + d4];
                float g0 = lds[OFF_G + u0 * 68 + k];
                float g1 = lds[OFF_G + u1c * 68 + k];
                a0x += g0 * w.x; a0y += g0 * w.y; a0z += g0 * w.z; a0w += g0 * w.w;
                a1x += g1 * w.x; a1y += g1 * w.y; a1z += g1 * w.z; a1w += g1 * w.w;
            }
            float4 bb = *(const float4*)&b2[d4];
            float4 f0 = {tanhf(a0x + bb.x), tanhf(a0y + bb.y),
                         tanhf(a0z + bb.z), tanhf(a0w + bb.w)};
            *(float4*)&lds[OFF_F + u0 * 68 + d4] = f0;
            if (has_u1) {
                float4 f1v = {tanhf(a1x + bb.x), tanhf(a1y + bb.y),
                              tanhf(a1z + bb.z), tanhf(a1w + bb.w)};
                *(float4*)&lds[OFF_F + u1 * 68 + d4] = f1v;
            }
        }
        __syncthreads();

        // ---- P6: z = sig(cat@Wz+bz), r = sig(cat@Wr+br), rh = r*h ----
        float z0x, z0y, z0z, z0w, z1x, z1y, z1z, z1w;
        float h0x, h0y, h0z, h0w, h1x, h1y, h1z, h1w;
        {
            float4 bz4 = *(const float4*)&bz[d4];
            float4 br4 = *(const float4*)&br[d4];
            float az0x = bz4.x, az0y = bz4.y, az0z = bz4.z, az0w = bz4.w;
            float az1x = bz4.x, az1y = bz4.y, az1z = bz4.z, az1w = bz4.w;
            float ar0x = br4.x, ar0y = br4.y, ar0z = br4.z, ar0w = br4.w;
            float ar1x = br4.x, ar1y = br4.y, ar1z = br4.z, ar1w = br4.w;
            // k = 0..3 : xt part
            for (int k = 0; k < 4; ++k) {
                float4 wz = *(const float4*)&Wz[k * 64 + d4];
                float4 wr = *(const float4*)&Wr[k * 64 + d4];
                float c0 = lds[OFF_XT + u0 * 4 + k];
                float c1 = lds[OFF_XT + u1c * 4 + k];
                az0x += c0 * wz.x; az0y += c0 * wz.y; az0z += c0 * wz.z; az0w += c0 * wz.w;
                az1x += c1 * wz.x; az1y += c1 * wz.y; az1z += c1 * wz.z; az1w += c1 * wz.w;
                ar0x += c0 * wr.x; ar0y += c0 * wr.y; ar0z += c0 * wr.z; ar0w += c0 * wr.w;
                ar1x += c1 * wr.x; ar1y += c1 * wr.y; ar1z += c1 * wr.z; ar1w += c1 * wr.w;
            }
            // k = 4..67 : f part
            for (int e = 0; e < D_; ++e) {
                int k = 4 + e;
                float4 wz = *(const float4*)&Wz[k * 64 + d4];
                float4 wr = *(const float4*)&Wr[k * 64 + d4];
                float c0 = lds[OFF_F + u0 * 68 + e];
                float c1 = lds[OFF_F + u1c * 68 + e];
                az0x += c0 * wz.x; az0y += c0 * wz.y; az0z += c0 * wz.z; az0w += c0 * wz.w;
                az1x += c1 * wz.x; az1y += c1 * wz.y; az1z += c1 * wz.z; az1w += c1 * wz.w;
                ar0x += c0 * wr.x; ar0y += c0 * wr.y; ar0z += c0 * wr.z; ar0w += c0 * wr.w;
                ar1x += c1 * wr.x; ar1y += c1 * wr.y; ar1z += c1 * wr.z; ar1w += c1 * wr.w;
            }
            // k = 68..131 : h part
            for (int e = 0; e < D_; ++e) {
                int k = 68 + e;
                float4 wz = *(const float4*)&Wz[k * 64 + d4];
                float4 wr = *(const float4*)&Wr[k * 64 + d4];
                float c0 = lds[OFF_H + u0 * 68 + e];
                float c1 = lds[OFF_H + u1c * 68 + e];
                az0x += c0 * wz.x; az0y += c0 * wz.y; az0z += c0 * wz.z; az0w += c0 * wz.w;
                az1x += c1 * wz.x; az1y += c1 * wz.y; az1z += c1 * wz.z; az1w += c1 * wz.w;
                ar0x += c0 * wr.x; ar0y += c0 * wr.y; ar0z += c0 * wr.z; ar0w += c0 * wr.w;
                ar1x += c1 * wr.x; ar1y += c1 * wr.y; ar1z += c1 * wr.z; ar1w += c1 * wr.w;
            }
            z0x = sigmoidf_(az0x); z0y = sigmoidf_(az0y);
            z0z = sigmoidf_(az0z); z0w = sigmoidf_(az0w);
            z1x = sigmoidf_(az1x); z1y = sigmoidf_(az1y);
            z1z = sigmoidf_(az1z); z1w = sigmoidf_(az1w);
            float r0x = sigmoidf_(ar0x), r0y = sigmoidf_(ar0y),
                  r0z = sigmoidf_(ar0z), r0w = sigmoidf_(ar0w);
            float r1x = sigmoidf_(ar1x), r1y = sigmoidf_(ar1y),
                  r1z = sigmoidf_(ar1z), r1w = sigmoidf_(ar1w);
            float4 h0 = *(const float4*)&lds[OFF_H + u0 * 68 + d4];
            h0x = h0.x; h0y = h0.y; h0z = h0.z; h0w = h0.w;
            float4 rh0 = {r0x * h0x, r0y * h0y, r0z * h0z, r0w * h0w};
            *(float4*)&lds[OFF_RH + u0 * 68 + d4] = rh0;
            float4 h1 = *(const float4*)&lds[OFF_H + u1c * 68 + d4];
            h1x = h1.x; h1y = h1.y; h1z = h1.z; h1w = h1.w;
            if (has_u1) {
                float4 rh1 = {r1x * h1x, r1y * h1y, r1z * h1z, r1w * h1w};
                *(float4*)&lds[OFF_RH + u1 * 68 + d4] = rh1;
            }
        }
        __syncthreads();

        // ---- P7: cn = tanh(cat2 @ Ww + bw); h = (1-z)h + z*cn ----
        {
            float4 bw4 = *(const float4*)&bw[d4];
            float aw0x = bw4.x, aw0y = bw4.y, aw0z = bw4.z, aw0w = bw4.w;
            float aw1x = bw4.x, aw1y = bw4.y, aw1z = bw4.z, aw1w = bw4.w;
            for (int k = 0; k < 4; ++k) {
                float4 ww = *(const float4*)&Ww[k * 64 + d4];
                float c0 = lds[OFF_XT + u0 * 4 + k];
                float c1 = lds[OFF_XT + u1c * 4 + k];
                aw0x += c0 * ww.x; aw0y += c0 * ww.y; aw0z += c0 * ww.z; aw0w += c0 * ww.w;
                aw1x += c1 * ww.x; aw1y += c1 * ww.y; aw1z += c1 * ww.z; aw1w += c1 * ww.w;
            }
            for (int e = 0; e < D_; ++e) {
                int k = 4 + e;
                float4 ww = *(const float4*)&Ww[k * 64 + d4];
                float c0 = lds[OFF_F + u0 * 68 + e];
                float c1 = lds[OFF_F + u1c * 68 + e];
                aw0x += c0 * ww.x; aw0y += c0 * ww.y; aw0z += c0 * ww.z; aw0w += c0 * ww.w;
                aw1x += c1 * ww.x; aw1y += c1 * ww.y; aw1z += c1 * ww.z; aw1w += c1 * ww.w;
            }
            for (int e = 0; e < D_; ++e) {
                int k = 68 + e;
                float4 ww = *(const float4*)&Ww[k * 64 + d4];
                float c0 = lds[OFF_RH + u0 * 68 + e];
                float c1 = lds[OFF_RH + u1c * 68 + e];
                aw0x += c0 * ww.x; aw0y += c0 * ww.y; aw0z += c0 * ww.z; aw0w += c0 * ww.w;
                aw1x += c1 * ww.x; aw1y += c1 * ww.y; aw1z += c1 * ww.z; aw1w += c1 * ww.w;
            }
            float cn0x = tanhf(aw0x), cn0y = tanhf(aw0y),
                  cn0z = tanhf(aw0z), cn0w = tanhf(aw0w);
            float4 hn0 = {(1.0f - z0x) * h0x + z0x * cn0x,
                          (1.0f - z0y) * h0y + z0y * cn0y,
                          (1.0f - z0z) * h0z + z0z * cn0z,
                          (1.0f - z0w) * h0w + z0w * cn0w};
            *(float4*)&lds[OFF_H + u0 * 68 + d4] = hn0;
            if (has_u1) {
                float cn1x = tanhf(aw1x), cn1y = tanhf(aw1y),
                      cn1z = tanhf(aw1z), cn1w = tanhf(aw1w);
                float4 hn1 = {(1.0f - z1x) * h1x + z1x * cn1x,
                              (1.0f - z1y) * h1y + z1y * cn1y,
                              (1.0f - z1z) * h1z + z1z * cn1z,
                              (1.0f - z1w) * h1w + z1w * cn1w};
                *(float4*)&lds[OFF_H + u1 * 68 + d4] = hn1;
            }
        }
        __syncthreads();   // protects s_xt / s_f / s_h for next step
    }

    // ---- P8: a = relu(h_flat @ Wf1 + bf1)  (128) ----
    {
        int j = tid & 127, part = tid >> 7;   // 8 parts x 808 k's
        float acc = 0.0f;
        int k0 = part * 808, k1 = k0 + 808;
        for (int k = k0; k < k1; ++k) {
            int v = k >> 6, dd = k & 63;
            acc += lds[OFF_H + v * 68 + dd] * Wf1[k * 128 + j];
        }
        lds[OFF_G + part * 128 + j] = acc;   // scratch (g is dead)
    }
    __syncthreads();
    if (tid < HID_) {
        float s = bf1[tid];
        for (int p = 0; p < 8; ++p) s += lds[OFF_G + p * 128 + tid];
        lds[OFF_RH + tid] = fmaxf(s, 0.0f);  // a[] in rh scratch
    }
    __syncthreads();

    // ---- P9: logits + softmax ----
    if (tid < V_) {
        float s = bf2[tid];
        for (int j = 0; j < HID_; ++j)
            s += lds[OFF_RH + j] * Wf2[j * V_ + tid];
        lds[OFF_G + tid] = s;                // logits
    }
    __syncthreads();
    if (tid < V_) {
        float m = -1e30f;
        for (int u = 0; u < V_; ++u) m = fmaxf(m, lds[OFF_G + u]);
        lds[OFF_G + 128 + tid] = expf(lds[OFF_G + tid] - m);
    }
    __syncthreads();
    if (tid < V_) {
        float s = 0.0f;
        for (int u = 0; u < V_; ++u) s += lds[OFF_G + 128 + u];
        out[(long long)b * V_ + tid] = lds[OFF_G + 128 + tid] / s;
    }
}

extern "C" void kernel_launch(void* const* d_in, const int* in_sizes, int n_in,
                              void* d_out, int out_size, void* d_ws, size_t ws_size,
                              hipStream_t stream) {
    const float* x   = (const float*)d_in[0];
    const float* dyn = (const float*)d_in[1];
    const float* W1  = (const float*)d_in[2];
    const float* b1  = (const float*)d_in[3];
    const float* W2  = (const float*)d_in[4];
    const float* b2  = (const float*)d_in[5];
    const float* Wz  = (const float*)d_in[6];
    const float* bz  = (const float*)d_in[7];
    const float* Wr  = (const float*)d_in[8];
    const float* br  = (const float*)d_in[9];
    const float* Ww  = (const float*)d_in[10];
    const float* bw  = (const float*)d_in[11];
    const float* Wf1 = (const float*)d_in[12];
    const float* bf1 = (const float*)d_in[13];
    const float* Wf2 = (const float*)d_in[14];
    const float* bf2 = (const float*)d_in[15];
    float* out = (float*)d_out;

    static_assert(LDS_FLOATS * 4 == 153936, "lds size");
    (void)hipFuncSetAttribute((const void*)mgcgru_fused,
                              hipFuncAttributeMaxDynamicSharedMemorySize,
                              LDS_FLOATS * 4);
    mgcgru_fused<<<B_, 1024, LDS_FLOATS * 4, stream>>>(
        x, dyn, W1, b1, W2, b2, Wz, bz, Wr, br, Ww, bw, Wf1, bf1, Wf2, bf2, out);
}

// Round 2
// 18257.898 us; speedup vs baseline: 42.2605x; 42.2605x over previous
//
#include <hip/hip_runtime.h>
#include <cmath>

#define B_    8192
#define V_    101
#define T_    30
#define C_    4
#define D_    64
#define HID_  128

typedef __attribute__((ext_vector_type(8))) short  short8;
typedef __attribute__((ext_vector_type(4))) float  f32x4;

#define MFMA16(a, b, c) __builtin_amdgcn_mfma_f32_16x16x32_bf16((a), (b), (c), 0, 0, 0)

// ---------------- LDS layout (ushort units, total 78592 ush = 157184 B) ----
// All strides are multiples of 8 with (stride/8) odd -> conflict-friendly frags.
#define DYN_OFF   0        // [128][136] bf16 dyn, rows/cols >=101 zero
#define CA_OFF    17408    // [128][168] bf16 cat: k 0..63 f, 64..127 h, 128..131 xt, 132..159 zero
#define GRH_OFF   38912    // [128][72]  bf16: g (P4->P5), then r*h (P6r->P7)
#define F1T_OFF   48128    // [64][136] f1^T (P3->P4); region (10752 ush) also stages Wr [64][168]
#define SB_OFF    58880    // [64][168] weight stage: Wz (P5->P6z), then Ww (P6r->P7)
#define W2T_OFF   69632    // [64][72]  W2^T bf16, resident
#define XBT_OFF   74240    // [16][136] xt^T bf16 (rows c 0..3, rest zero)
#define YF_OFF    38208    // FLOAT offset: y [128][4]; also head scratch (512 floats)
#define W1F_OFF   38720    // FLOAT offset: W1[256], b1[64], b2[64], bz[64], br[64], bw[64]
#define LDS_USH   78592

__device__ __forceinline__ unsigned short f2b(float f) {
    unsigned u = __float_as_uint(f);
    u += 0x7fffu + ((u >> 16) & 1u);          // round-to-nearest-even
    return (unsigned short)(u >> 16);
}
__device__ __forceinline__ float b2f(unsigned short h) {
    return __uint_as_float(((unsigned)h) << 16);
}

// ---------------- kernel 0: build bf16 LDS images in workspace -------------
__global__ void build_images(const float* __restrict__ dyn,
                             const float* __restrict__ Wz, const float* __restrict__ Wr,
                             const float* __restrict__ Ww, const float* __restrict__ W2,
                             unsigned short* __restrict__ dimg,
                             unsigned short* __restrict__ zimg,
                             unsigned short* __restrict__ rimg,
                             unsigned short* __restrict__ wimg,
                             unsigned short* __restrict__ w2img)
{
    int tid = blockIdx.x * blockDim.x + threadIdx.x;
    int nth = gridDim.x * blockDim.x;
    for (int i = tid; i < 128 * 136; i += nth) {
        int u = i / 136, v = i - u * 136;
        dimg[i] = (u < V_ && v < V_) ? f2b(dyn[u * V_ + v]) : (unsigned short)0;
    }
    // gate weights: transposed [n][k'] with k' reorder: 0..127 <- rows k'+4 (f,h), 128..131 <- rows 0..3 (xt)
    for (int i = tid; i < 64 * 168; i += nth) {
        int n = i / 168, k = i - n * 168;
        unsigned short vz = 0, vr = 0, vw = 0;
        if (k < 132) {
            int gk = (k < 128) ? (k + 4) : (k - 128);
            vz = f2b(Wz[gk * 64 + n]);
            vr = f2b(Wr[gk * 64 + n]);
            vw = f2b(Ww[gk * 64 + n]);
        }
        zimg[i] = vz; rimg[i] = vr; wimg[i] = vw;
    }
    for (int i = tid; i < 64 * 72; i += nth) {
        int n = i / 72, k = i - n * 72;
        w2img[i] = (k < 64) ? f2b(W2[k * 64 + n]) : (unsigned short)0;
    }
}

// ---------------- kernel 1: fused recurrent MFMA kernel --------------------
__global__ void __launch_bounds__(1024, 4)
mgcgru_mfma(const float* __restrict__ x,
            const unsigned short* __restrict__ dimg,
            const unsigned short* __restrict__ zimg,
            const unsigned short* __restrict__ rimg,
            const unsigned short* __restrict__ wimg,
            const unsigned short* __restrict__ w2img,
            const float* __restrict__ W1, const float* __restrict__ b1,
            const float* __restrict__ b2, const float* __restrict__ bz,
            const float* __restrict__ br, const float* __restrict__ bw,
            const float* __restrict__ Wf1, const float* __restrict__ bf1,
            const float* __restrict__ Wf2, const float* __restrict__ bf2,
            unsigned short* __restrict__ wsflat,
            float* __restrict__ out, int mode)
{
    extern __shared__ unsigned short sm[];
    float* smf = (float*)sm;
    const int tid  = threadIdx.x;
    const int b    = blockIdx.x;
    const int wv   = tid >> 6;
    const int lane = tid & 63;
    const int l16  = lane & 15;
    const int quad = lane >> 4;
    const int mt   = wv & 7;                 // M-tile (rows mt*16..mt*16+15)
    const int nt0  = (wv >> 3) * 2;          // owns N-tiles nt0, nt0+1

    // ---- init: zero LDS, copy resident images, fp32 params ----
    {
        unsigned* p = (unsigned*)sm;
        for (int i = tid; i < LDS_USH / 2; i += 1024) p[i] = 0u;
    }
    __syncthreads();
    {
        const uint4* g = (const uint4*)dimg;
        uint4* d = (uint4*)&sm[DYN_OFF];
        for (int i = tid; i < (128 * 136) / 8; i += 1024) d[i] = g[i];
    }
    {
        const uint4* g = (const uint4*)w2img;
        uint4* d = (uint4*)&sm[W2T_OFF];
        for (int i = tid; i < (64 * 72) / 8; i += 1024) d[i] = g[i];
    }
    for (int i = tid; i < 576; i += 1024) {
        float v;
        if      (i < 256) v = W1[i];
        else if (i < 320) v = b1[i - 256];
        else if (i < 384) v = b2[i - 320];
        else if (i < 448) v = bz[i - 384];
        else if (i < 512) v = br[i - 448];
        else              v = bw[i - 512];
        smf[W1F_OFF + i] = v;
    }

    float hreg[2][4] = {{0.f,0.f,0.f,0.f},{0.f,0.f,0.f,0.f}};
    float zreg[2][4];
    __syncthreads();

    const float* xb = x + (size_t)b * (V_ * T_ * C_);

    for (int t = 0; t < T_; ++t) {
        // ---- P1: xt -> CA cols 128..131 and XBT ----
        if (tid < V_ * C_) {
            int v = tid >> 2, c = tid & 3;
            unsigned short h16 = f2b(xb[v * (T_ * C_) + t * C_ + c]);
            sm[CA_OFF + v * 168 + 128 + c] = h16;
            sm[XBT_OFF + c * 136 + v]      = h16;
        }
        __syncthreads();

        // ---- P2: y = dyn @ xt  (waves 0..7, one M-tile each) ----
        if (wv < 8) {
            f32x4 acc = {0.f, 0.f, 0.f, 0.f};
            for (int kt = 0; kt < 4; ++kt) {
                short8 a  = *(const short8*)&sm[DYN_OFF + (wv*16 + l16)*136 + kt*32 + quad*8];
                short8 bb = *(const short8*)&sm[XBT_OFF + l16*136 + kt*32 + quad*8];
                acc = MFMA16(a, bb, acc);
            }
            if (l16 < 4) {
                #pragma unroll
                for (int e = 0; e < 4; ++e)
                    smf[YF_OFF + (wv*16 + quad*4 + e) * 4 + l16] = acc[e];
            }
        }
        __syncthreads();

        // ---- P3: f1 = tanh(y@W1 + b1) -> F1T (transposed [d][v]) ----
        {
            int u = tid & 127, db = (tid >> 7) * 8;
            float y0 = smf[YF_OFF + u*4 + 0], y1 = smf[YF_OFF + u*4 + 1];
            float y2 = smf[YF_OFF + u*4 + 2], y3 = smf[YF_OFF + u*4 + 3];
            #pragma unroll
            for (int j = 0; j < 8; ++j) {
                int d = db + j;
                float acc = smf[W1F_OFF + 256 + d]
                          + y0 * smf[W1F_OFF + 0*64 + d] + y1 * smf[W1F_OFF + 1*64 + d]
                          + y2 * smf[W1F_OFF + 2*64 + d] + y3 * smf[W1F_OFF + 3*64 + d];
                sm[F1T_OFF + d * 136 + u] = f2b(tanhf(acc));
            }
        }
        __syncthreads();

        // ---- P4: g = dyn @ f1 -> GRH ----
        {
            f32x4 a0 = {0.f,0.f,0.f,0.f}, a1 = {0.f,0.f,0.f,0.f};
            for (int kt = 0; kt < 4; ++kt) {
                short8 a  = *(const short8*)&sm[DYN_OFF + (mt*16 + l16)*136 + kt*32 + quad*8];
                short8 bA = *(const short8*)&sm[F1T_OFF + (nt0*16 + l16)*136 + kt*32 + quad*8];
                short8 bB = *(const short8*)&sm[F1T_OFF + ((nt0+1)*16 + l16)*136 + kt*32 + quad*8];
                a0 = MFMA16(a, bA, a0);
                a1 = MFMA16(a, bB, a1);
            }
            #pragma unroll
            for (int e = 0; e < 4; ++e) {
                int row = mt*16 + quad*4 + e;
                sm[GRH_OFF + row*72 + nt0*16 + l16]     = f2b(a0[e]);
                sm[GRH_OFF + row*72 + (nt0+1)*16 + l16] = f2b(a1[e]);
            }
        }
        __syncthreads();

        // ---- P5: f = tanh(g@W2 + b2) -> CA cols 0..63 ; stage Wz -> SB ----
        {
            const uint4* gz = (const uint4*)zimg;
            uint4 p0 = gz[tid];
            uint4 p1; if (tid < 320) p1 = gz[tid + 1024];
            f32x4 a0 = {0.f,0.f,0.f,0.f}, a1 = {0.f,0.f,0.f,0.f};
            for (int kt = 0; kt < 2; ++kt) {
                short8 a  = *(const short8*)&sm[GRH_OFF + (mt*16 + l16)*72 + kt*32 + quad*8];
                short8 bA = *(const short8*)&sm[W2T_OFF + (nt0*16 + l16)*72 + kt*32 + quad*8];
                short8 bB = *(const short8*)&sm[W2T_OFF + ((nt0+1)*16 + l16)*72 + kt*32 + quad*8];
                a0 = MFMA16(a, bA, a0);
                a1 = MFMA16(a, bB, a1);
            }
            #pragma unroll
            for (int e = 0; e < 4; ++e) {
                int row = mt*16 + quad*4 + e;
                int c0 = nt0*16 + l16, c1 = c0 + 16;
                sm[CA_OFF + row*168 + c0] = f2b(tanhf(a0[e] + smf[W1F_OFF + 320 + c0]));
                sm[CA_OFF + row*168 + c1] = f2b(tanhf(a1[e] + smf[W1F_OFF + 320 + c1]));
            }
            ((uint4*)&sm[SB_OFF])[tid] = p0;
            if (tid < 320) ((uint4*)&sm[SB_OFF])[tid + 1024] = p1;
        }
        __syncthreads();

        // ---- P6z: z = sigmoid(cat@Wz + bz) (kept in regs); stage Wr -> F1T region ----
        {
            const uint4* gr = (const uint4*)rimg;
            uint4 p0 = gr[tid];
            uint4 p1; if (tid < 320) p1 = gr[tid + 1024];
            f32x4 a0 = {0.f,0.f,0.f,0.f}, a1 = {0.f,0.f,0.f,0.f};
            for (int kt = 0; kt < 5; ++kt) {
                short8 a  = *(const short8*)&sm[CA_OFF + (mt*16 + l16)*168 + kt*32 + quad*8];
                short8 bA = *(const short8*)&sm[SB_OFF + (nt0*16 + l16)*168 + kt*32 + quad*8];
                short8 bB = *(const short8*)&sm[SB_OFF + ((nt0+1)*16 + l16)*168 + kt*32 + quad*8];
                a0 = MFMA16(a, bA, a0);
                a1 = MFMA16(a, bB, a1);
            }
            #pragma unroll
            for (int e = 0; e < 4; ++e) {
                int c0 = nt0*16 + l16, c1 = c0 + 16;
                zreg[0][e] = 1.f / (1.f + expf(-(a0[e] + smf[W1F_OFF + 384 + c0])));
                zreg[1][e] = 1.f / (1.f + expf(-(a1[e] + smf[W1F_OFF + 384 + c1])));
            }
            ((uint4*)&sm[F1T_OFF])[tid] = p0;
            if (tid < 320) ((uint4*)&sm[F1T_OFF])[tid + 1024] = p1;
        }
        __syncthreads();

        // ---- P6r: r = sigmoid(cat@Wr + br); r*h -> GRH ; stage Ww -> SB ----
        {
            const uint4* gw = (const uint4*)wimg;
            uint4 p0 = gw[tid];
            uint4 p1; if (tid < 320) p1 = gw[tid + 1024];
            f32x4 a0 = {0.f,0.f,0.f,0.f}, a1 = {0.f,0.f,0.f,0.f};
            for (int kt = 0; kt < 5; ++kt) {
                short8 a  = *(const short8*)&sm[CA_OFF + (mt*16 + l16)*168 + kt*32 + quad*8];
                short8 bA = *(const short8*)&sm[F1T_OFF + (nt0*16 + l16)*168 + kt*32 + quad*8];
                short8 bB = *(const short8*)&sm[F1T_OFF + ((nt0+1)*16 + l16)*168 + kt*32 + quad*8];
                a0 = MFMA16(a, bA, a0);
                a1 = MFMA16(a, bB, a1);
            }
            #pragma unroll
            for (int e = 0; e < 4; ++e) {
                int row = mt*16 + quad*4 + e;
                int c0 = nt0*16 + l16, c1 = c0 + 16;
                float r0 = 1.f / (1.f + expf(-(a0[e] + smf[W1F_OFF + 448 + c0])));
                float r1 = 1.f / (1.f + expf(-(a1[e] + smf[W1F_OFF + 448 + c1])));
                sm[GRH_OFF + row*72 + c0] = f2b(r0 * hreg[0][e]);
                sm[GRH_OFF + row*72 + c1] = f2b(r1 * hreg[1][e]);
            }
            ((uint4*)&sm[SB_OFF])[tid] = p0;
            if (tid < 320) ((uint4*)&sm[SB_OFF])[tid + 1024] = p1;
        }
        __syncthreads();

        // ---- P7: cn = tanh(cat2@Ww + bw); h = h + z*(cn-h); h -> CA cols 64..127 ----
        {
            f32x4 a0 = {0.f,0.f,0.f,0.f}, a1 = {0.f,0.f,0.f,0.f};
            for (int kt = 0; kt < 5; ++kt) {
                short8 a;
                if (kt < 2)
                    a = *(const short8*)&sm[CA_OFF + (mt*16 + l16)*168 + kt*32 + quad*8];
                else if (kt < 4)
                    a = *(const short8*)&sm[GRH_OFF + (mt*16 + l16)*72 + (kt-2)*32 + quad*8];
                else
                    a = *(const short8*)&sm[CA_OFF + (mt*16 + l16)*168 + 128 + quad*8];
                short8 bA = *(const short8*)&sm[SB_OFF + (nt0*16 + l16)*168 + kt*32 + quad*8];
                short8 bB = *(const short8*)&sm[SB_OFF + ((nt0+1)*16 + l16)*168 + kt*32 + quad*8];
                a0 = MFMA16(a, bA, a0);
                a1 = MFMA16(a, bB, a1);
            }
            #pragma unroll
            for (int e = 0; e < 4; ++e) {
                int row = mt*16 + quad*4 + e;
                int c0 = nt0*16 + l16, c1 = c0 + 16;
                float cn0 = tanhf(a0[e] + smf[W1F_OFF + 512 + c0]);
                float cn1 = tanhf(a1[e] + smf[W1F_OFF + 512 + c1]);
                float h0 = hreg[0][e] + zreg[0][e] * (cn0 - hreg[0][e]);
                float h1 = hreg[1][e] + zreg[1][e] * (cn1 - hreg[1][e]);
                hreg[0][e] = h0; hreg[1][e] = h1;
                sm[CA_OFF + row*168 + 64 + c0] = f2b(h0);
                sm[CA_OFF + row*168 + 64 + c1] = f2b(h1);
            }
        }
        __syncthreads();
    } // t loop

    if (mode == 1) {
        // write flat h (bf16) to workspace for the head GEMM
        if (tid < 808) {
            int v = tid >> 3, d8 = (tid & 7) * 8;
            uint4 val = *(const uint4*)&sm[CA_OFF + v*168 + 64 + d8];
            *(uint4*)(wsflat + (size_t)b * 6464 + v * 64 + d8) = val;
        }
    } else {
        // fallback: in-block head (slow but correct)
        {
            int j = tid & 127, part = tid >> 7;
            float acc = 0.f;
            int k0 = part * 808;
            for (int k = k0; k < k0 + 808; ++k) {
                int v = k >> 6, d = k & 63;
                acc += b2f(sm[CA_OFF + v*168 + 64 + d]) * Wf1[(size_t)k * 128 + j];
            }
            smf[SB_OFF / 2 + part * 128 + j] = acc;
        }
        __syncthreads();
        if (tid < 128) {
            float s = bf1[tid];
            for (int p = 0; p < 8; ++p) s += smf[SB_OFF / 2 + p * 128 + tid];
            smf[YF_OFF + 128 + tid] = fmaxf(s, 0.f);
        }
        __syncthreads();
        for (int i = tid; i < 128 * 101; i += 1024) smf[i] = Wf2[i];  // DYN/CA dead now
        __syncthreads();
        if (tid < V_) {
            float s = bf2[tid];
            for (int j = 0; j < 128; ++j) s += smf[YF_OFF + 128 + j] * smf[j * 101 + tid];
            smf[YF_OFF + 256 + tid] = s;
        }
        __syncthreads();
        if (tid < V_) {
            float m = -1e30f;
            for (int u = 0; u < V_; ++u) m = fmaxf(m, smf[YF_OFF + 256 + u]);
            smf[YF_OFF + 384 + tid] = expf(smf[YF_OFF + 256 + tid] - m);
        }
        __syncthreads();
        if (tid < V_) {
            float s = 0.f;
            for (int u = 0; u < V_; ++u) s += smf[YF_OFF + 384 + u];
            out[(size_t)b * V_ + tid] = smf[YF_OFF + 384 + tid] / s;
        }
    }
}

// ---------------- kernel 2: A1 = relu(flat @ Wf1 + bf1) --------------------
__global__ void __launch_bounds__(256)
head1_gemm(const unsigned short* __restrict__ flat,   // [8192][6464] bf16
           const float* __restrict__ Wf1,             // [6464][128]
           const float* __restrict__ bf1,
           float* __restrict__ A1)                    // [8192][128]
{
    __shared__ __align__(16) unsigned short AT[32 * 40 + 128 * 40];
    unsigned short* BT = AT + 32 * 40;
    const int tid  = threadIdx.x;
    const int Mb   = blockIdx.x * 32;
    const int wv   = tid >> 6, lane = tid & 63;
    const int l16  = lane & 15, quad = lane >> 4;
    const int mt   = wv & 1;
    const int ntB  = (wv >> 1) * 4;
    f32x4 acc[4] = {{0.f,0.f,0.f,0.f},{0.f,0.f,0.f,0.f},{0.f,0.f,0.f,0.f},{0.f,0.f,0.f,0.f}};

    for (int kt = 0; kt < 202; ++kt) {
        uint4 av;
        if (tid < 128) {
            int row = tid >> 2, k8 = (tid & 3) * 8;
            av = *(const uint4*)(flat + (size_t)(Mb + row) * 6464 + kt * 32 + k8);
        }
        float4 bv[4];
        #pragma unroll
        for (int p = 0; p < 4; ++p) {
            int g = tid + p * 256, k = g >> 5, nq = g & 31;
            bv[p] = *(const float4*)&Wf1[(size_t)(kt * 32 + k) * 128 + nq * 4];
        }
        __syncthreads();
        if (tid < 128) {
            int row = tid >> 2, k8 = (tid & 3) * 8;
            *(uint4*)&AT[row * 40 + k8] = av;
        }
        #pragma unroll
        for (int p = 0; p < 4; ++p) {
            int g = tid + p * 256, k = g >> 5, nq = g & 31;
            BT[(nq*4 + 0) * 40 + k] = f2b(bv[p].x);
            BT[(nq*4 + 1) * 40 + k] = f2b(bv[p].y);
            BT[(nq*4 + 2) * 40 + k] = f2b(bv[p].z);
            BT[(nq*4 + 3) * 40 + k] = f2b(bv[p].w);
        }
        __syncthreads();
        short8 a = *(const short8*)&AT[(mt*16 + l16) * 40 + quad * 8];
        #pragma unroll
        for (int i = 0; i < 4; ++i) {
            short8 bb = *(const short8*)&BT[((ntB + i)*16 + l16) * 40 + quad * 8];
            acc[i] = MFMA16(a, bb, acc[i]);
        }
    }
    #pragma unroll
    for (int i = 0; i < 4; ++i)
        #pragma unroll
        for (int e = 0; e < 4; ++e) {
            int row = Mb + mt*16 + quad*4 + e;
            int col = (ntB + i)*16 + l16;
            A1[(size_t)row * 128 + col] = fmaxf(acc[i][e] + bf1[col], 0.f);
        }
}

// ---------------- kernel 3: out = softmax(A1 @ Wf2 + bf2) ------------------
__global__ void head2_softmax(const float* __restrict__ A1,
                              const float* __restrict__ Wf2,   // [128][101]
                              const float* __restrict__ bf2,
                              float* __restrict__ out)
{
    extern __shared__ float s3[];
    float* WF = s3;                 // 12928
    float* AR = s3 + 12928;         // 128
    float* LG = AR + 128;           // 104
    float* EG = LG + 104;           // 104
    const int tid = threadIdx.x;    // 128 threads
    for (int i = tid; i < 128 * 101; i += 128) WF[i] = Wf2[i];
    for (int r = 0; r < 64; ++r) {
        size_t row = (size_t)blockIdx.x * 64 + r;
        __syncthreads();
        AR[tid] = A1[row * 128 + tid];
        __syncthreads();
        if (tid < V_) {
            float s = bf2[tid];
            for (int j = 0; j < 128; ++j) s += AR[j] * WF[j * 101 + tid];
            LG[tid] = s;
        }
        __syncthreads();
        if (tid < V_) {
            float m = -1e30f;
            for (int u = 0; u < V_; ++u) m = fmaxf(m, LG[u]);
            EG[tid] = expf(LG[tid] - m);
        }
        __syncthreads();
        if (tid < V_) {
            float s = 0.f;
            for (int u = 0; u < V_; ++u) s += EG[u];
            out[row * 101 + tid] = EG[tid] / s;
        }
    }
}

extern "C" void kernel_launch(void* const* d_in, const int* in_sizes, int n_in,
                              void* d_out, int out_size, void* d_ws, size_t ws_size,
                              hipStream_t stream) {
    const float* x   = (const float*)d_in[0];
    const float* dyn = (const float*)d_in[1];
    const float* W1  = (const float*)d_in[2];
    const float* b1  = (const float*)d_in[3];
    const float* W2  = (const float*)d_in[4];
    const float* b2  = (const float*)d_in[5];
    const float* Wz  = (const float*)d_in[6];
    const float* bz  = (const float*)d_in[7];
    const float* Wr  = (const float*)d_in[8];
    const float* br  = (const float*)d_in[9];
    const float* Ww  = (const float*)d_in[10];
    const float* bw  = (const float*)d_in[11];
    const float* Wf1 = (const float*)d_in[12];
    const float* bf1 = (const float*)d_in[13];
    const float* Wf2 = (const float*)d_in[14];
    const float* bf2 = (const float*)d_in[15];
    float* out = (float*)d_out;

    const size_t FLAT_B = (size_t)B_ * 6464 * 2;          // 105,906,176
    const size_t A1_B   = (size_t)B_ * 128 * 4;           //   4,194,304
    const size_t IMG_B  = (size_t)(17408 + 3 * 10752 + 4608) * 2;  // 108,544
    int mode = (ws_size >= FLAT_B + A1_B + IMG_B) ? 1 : 0;

    char* wsc = (char*)d_ws;
    unsigned short* wsflat = nullptr;
    float* A1p = nullptr;
    unsigned short* img;
    if (mode) {
        wsflat = (unsigned short*)wsc;
        A1p    = (float*)(wsc + FLAT_B);
        img    = (unsigned short*)(wsc + FLAT_B + A1_B);
    } else {
        img    = (unsigned short*)wsc;   // needs only 108,544 B
    }
    unsigned short* dimg  = img;
    unsigned short* zimg  = dimg + 17408;
    unsigned short* rimg  = zimg + 10752;
    unsigned short* wimg  = rimg + 10752;
    unsigned short* w2img = wimg + 10752;

    build_images<<<64, 256, 0, stream>>>(dyn, Wz, Wr, Ww, W2,
                                         dimg, zimg, rimg, wimg, w2img);

    (void)hipFuncSetAttribute((const void*)mgcgru_mfma,
                              hipFuncAttributeMaxDynamicSharedMemorySize, LDS_USH * 2);
    mgcgru_mfma<<<B_, 1024, LDS_USH * 2, stream>>>(
        x, dimg, zimg, rimg, wimg, w2img,
        W1, b1, b2, bz, br, bw, Wf1, bf1, Wf2, bf2, wsflat, out, mode);

    if (mode) {
        head1_gemm<<<B_ / 32, 256, 0, stream>>>(wsflat, Wf1, bf1, A1p);
        head2_softmax<<<B_ / 64, 128, (12928 + 128 + 104 + 104) * 4, stream>>>(A1p, Wf2, bf2, out);
    }
}